// Round 1
// baseline (1555.503 us; speedup 1.0000x reference)
//
#include <hip/hip_runtime.h>
#include <hip/hip_bf16.h>

typedef __bf16 bf16_t;
typedef __bf16 bf16x8 __attribute__((ext_vector_type(8)));
typedef __bf16 bf16x4 __attribute__((ext_vector_type(4)));
typedef float f32x4 __attribute__((ext_vector_type(4)));
typedef int i32x4 __attribute__((ext_vector_type(4)));

__device__ __forceinline__ f32x4 mfma16(bf16x8 a, bf16x8 b, f32x4 c) {
  return __builtin_amdgcn_mfma_f32_16x16x32_bf16(a, b, c, 0, 0, 0);
}

// ---------------- ternary threshold: deterministic fp64 two-stage reduction ----------------
__global__ void abssum_stage1(const float* __restrict__ W, int n4, double* __restrict__ partial) {
  __shared__ double sd[256];
  const int tid = threadIdx.x;
  double s = 0.0;
  for (int i = blockIdx.x * 256 + tid; i < n4; i += gridDim.x * 256) {
    float4 v = ((const float4*)W)[i];
    s += (double)fabsf(v.x); s += (double)fabsf(v.y);
    s += (double)fabsf(v.z); s += (double)fabsf(v.w);
  }
  sd[tid] = s; __syncthreads();
  for (int st = 128; st > 0; st >>= 1) { if (tid < st) sd[tid] += sd[tid + st]; __syncthreads(); }
  if (tid == 0) partial[blockIdx.x] = sd[0];
}

__global__ void abssum_stage2(const double* __restrict__ partial, double* __restrict__ out) {
  __shared__ double sd[256];
  const int tid = threadIdx.x;
  double s = partial[tid] + partial[tid + 256] + partial[tid + 512] + partial[tid + 768];
  sd[tid] = s; __syncthreads();
  for (int st = 128; st > 0; st >>= 1) { if (tid < st) sd[tid] += sd[tid + st]; __syncthreads(); }
  if (tid == 0) out[0] = sd[0];
}

__global__ void ternarize_k(const float* __restrict__ W, bf16_t* __restrict__ out,
                            const double* __restrict__ sum, double n) {
  const double thr = sum[0] / n;
  const int i = blockIdx.x * 256 + threadIdx.x;  // float4 index; grid sized exactly
  float4 v = ((const float4*)W)[i];
  bf16x4 o;
  float t;
  t = ((double)fabsf(v.x) > thr) ? (v.x > 0.f ? 1.f : -1.f) : 0.f; o[0] = (bf16_t)t;
  t = ((double)fabsf(v.y) > thr) ? (v.y > 0.f ? 1.f : -1.f) : 0.f; o[1] = (bf16_t)t;
  t = ((double)fabsf(v.z) > thr) ? (v.z > 0.f ? 1.f : -1.f) : 0.f; o[2] = (bf16_t)t;
  t = ((double)fabsf(v.w) > thr) ? (v.w > 0.f ? 1.f : -1.f) : 0.f; o[3] = (bf16_t)t;
  *(bf16x4*)&out[(size_t)i * 4] = o;
}

// ---------------- x -> hi/lo bf16 split ----------------
__global__ void split_x_k(const float* __restrict__ X, bf16_t* __restrict__ xh, bf16_t* __restrict__ xl) {
  const int i = blockIdx.x * 256 + threadIdx.x;  // float4 index; total 2,097,152
  float4 v = ((const float4*)X)[i];
  bf16x4 h, l;
  h[0] = (bf16_t)v.x; l[0] = (bf16_t)(v.x - (float)h[0]);
  h[1] = (bf16_t)v.y; l[1] = (bf16_t)(v.y - (float)h[1]);
  h[2] = (bf16_t)v.z; l[2] = (bf16_t)(v.z - (float)h[2]);
  h[3] = (bf16_t)v.w; l[3] = (bf16_t)(v.w - (float)h[3]);
  *(bf16x4*)&xh[(size_t)i * 4] = h;
  *(bf16x4*)&xl[(size_t)i * 4] = l;
}

// ---------------- GEMM: C[t][o] = sum_k A[t][k] * W[o][k]  (W ternary bf16, [N][K] row-major) ----
// EPI: 0 = split-store (C0=hi bf16, C1=lo bf16), 1 = vT transposed bf16 store,
//      2 = f32 store, 3 = relu bf16 store
template <int EPI, bool SPLITA>
__global__ __launch_bounds__(256, 2) void gemm_tn(
    const bf16_t* __restrict__ Ah, const bf16_t* __restrict__ Al,
    const bf16_t* __restrict__ Bw,
    void* __restrict__ C0, void* __restrict__ C1,
    int M, int N, int K) {
  constexpr int BK = 32;
  __shared__ __align__(16) bf16_t sA[128 * BK];
  __shared__ __align__(16) bf16_t sA2[SPLITA ? 128 * BK : 8];
  __shared__ __align__(16) bf16_t sB[128 * BK];

  const int tid = threadIdx.x;
  const size_t Ks = (size_t)K;
  const size_t m0 = (size_t)blockIdx.y * 128, n0 = (size_t)blockIdx.x * 128;
  const int lane = tid & 63, wv = tid >> 6, lr = lane & 15, lg = lane >> 4;
  const int wr = wv >> 1, wc = wv & 1;
  const int f0 = tid, f1 = tid + 256;
  const int r0 = f0 >> 2, c0 = (f0 & 3) * 8, r1 = f1 >> 2, c1 = (f1 & 3) * 8;

  f32x4 acc[4][4] = {};
  i32x4 a0, a1, a2, a3, b0, b1;
  const int nt = K / BK;

  auto LOADT = [&](int kt) {
    size_t ko = (size_t)kt * BK;
    a0 = *(const i32x4*)(Ah + (m0 + r0) * Ks + ko + c0);
    a1 = *(const i32x4*)(Ah + (m0 + r1) * Ks + ko + c1);
    if constexpr (SPLITA) {
      a2 = *(const i32x4*)(Al + (m0 + r0) * Ks + ko + c0);
      a3 = *(const i32x4*)(Al + (m0 + r1) * Ks + ko + c1);
    }
    b0 = *(const i32x4*)(Bw + (n0 + r0) * Ks + ko + c0);
    b1 = *(const i32x4*)(Bw + (n0 + r1) * Ks + ko + c1);
  };
  auto WRT = [&]() {
    *(i32x4*)&sA[f0 * 8] = a0; *(i32x4*)&sA[f1 * 8] = a1;
    if constexpr (SPLITA) { *(i32x4*)&sA2[f0 * 8] = a2; *(i32x4*)&sA2[f1 * 8] = a3; }
    *(i32x4*)&sB[f0 * 8] = b0; *(i32x4*)&sB[f1 * 8] = b1;
  };

  LOADT(0); WRT(); __syncthreads();
  for (int kt = 0; kt < nt; kt++) {
    if (kt + 1 < nt) LOADT(kt + 1);
    bf16x8 afh[4], bfr[4];
#pragma unroll
    for (int n = 0; n < 4; n++) bfr[n] = *(const bf16x8*)&sB[(wc * 64 + n * 16 + lr) * BK + lg * 8];
#pragma unroll
    for (int m = 0; m < 4; m++) afh[m] = *(const bf16x8*)&sA[(wr * 64 + m * 16 + lr) * BK + lg * 8];
#pragma unroll
    for (int m = 0; m < 4; m++)
#pragma unroll
      for (int n = 0; n < 4; n++) acc[m][n] = mfma16(afh[m], bfr[n], acc[m][n]);
    if constexpr (SPLITA) {
#pragma unroll
      for (int m = 0; m < 4; m++) afh[m] = *(const bf16x8*)&sA2[(wr * 64 + m * 16 + lr) * BK + lg * 8];
#pragma unroll
      for (int m = 0; m < 4; m++)
#pragma unroll
        for (int n = 0; n < 4; n++) acc[m][n] = mfma16(afh[m], bfr[n], acc[m][n]);
    }
    if (kt + 1 < nt) { __syncthreads(); WRT(); __syncthreads(); }
  }

  const int row0 = (int)m0 + wr * 64, colb = (int)n0 + wc * 64;
#pragma unroll
  for (int m = 0; m < 4; m++)
#pragma unroll
    for (int n = 0; n < 4; n++)
#pragma unroll
      for (int j = 0; j < 4; j++) {
        const int r = row0 + m * 16 + lg * 4 + j;
        const int c = colb + n * 16 + lr;
        const float v = acc[m][n][j];
        if constexpr (EPI == 0) {
          bf16_t hi = (bf16_t)v;
          ((bf16_t*)C0)[(size_t)r * N + c] = hi;
          ((bf16_t*)C1)[(size_t)r * N + c] = (bf16_t)(v - (float)hi);
        } else if constexpr (EPI == 1) {
          const int bb = r >> 11, ss = r & 2047;
          ((bf16_t*)C0)[((size_t)bb * 2048 + c) * 2048 + ss] = (bf16_t)v;
        } else if constexpr (EPI == 2) {
          ((float*)C0)[(size_t)r * N + c] = v;
        } else {
          ((bf16_t*)C0)[(size_t)r * N + c] = (bf16_t)fmaxf(v, 0.f);
        }
      }
}

// ---------------- flash attention: q,k split hi/lo; vT is [b][h][d][s] ----------------
__global__ __launch_bounds__(256) void attn_k(
    const bf16_t* __restrict__ qh, const bf16_t* __restrict__ ql,
    const bf16_t* __restrict__ kh, const bf16_t* __restrict__ kl,
    const bf16_t* __restrict__ vT, bf16_t* __restrict__ out) {
  const int qt = blockIdx.x, bh = blockIdx.y;
  const int b = bh >> 4, h = bh & 15;
  const int wv = threadIdx.x >> 6, lane = threadIdx.x & 63, lr = lane & 15, lg = lane >> 4;
  const size_t tok0 = (size_t)b * 2048 + qt * 64 + wv * 16;
  __shared__ __align__(16) bf16_t plds[4][512];
  bf16_t* pw = &plds[wv][0];

  bf16x8 qhf[4], qlf[4];
  {
    const bf16_t* qp = qh + (tok0 + lr) * 2048 + h * 128 + lg * 8;
    const bf16_t* qp2 = ql + (tok0 + lr) * 2048 + h * 128 + lg * 8;
#pragma unroll
    for (int ks = 0; ks < 4; ks++) {
      qhf[ks] = *(const bf16x8*)(qp + ks * 32);
      qlf[ks] = *(const bf16x8*)(qp2 + ks * 32);
    }
  }
  f32x4 oacc[8] = {};
  float mrun[4] = {-1e30f, -1e30f, -1e30f, -1e30f};
  float lrun[4] = {0.f, 0.f, 0.f, 0.f};
  const size_t kvbase = ((size_t)b * 2048) * 2048 + (size_t)h * 128;
  const bf16_t* vbase = vT + ((size_t)b * 2048 + h * 128 + lr) * 2048;

  for (int kv0 = 0; kv0 < 2048; kv0 += 32) {
    f32x4 s[2] = {};
#pragma unroll
    for (int nb = 0; nb < 2; nb++) {
      const bf16_t* kp = kh + kvbase + (size_t)(kv0 + nb * 16 + lr) * 2048 + lg * 8;
      const bf16_t* kp2 = kl + kvbase + (size_t)(kv0 + nb * 16 + lr) * 2048 + lg * 8;
#pragma unroll
      for (int ks = 0; ks < 4; ks++) {
        bf16x8 kf = *(const bf16x8*)(kp + ks * 32);
        bf16x8 kg = *(const bf16x8*)(kp2 + ks * 32);
        s[nb] = mfma16(qhf[ks], kf, s[nb]);
        s[nb] = mfma16(qlf[ks], kf, s[nb]);
        s[nb] = mfma16(qhf[ks], kg, s[nb]);
      }
    }
    const float sc = 0.08838834764831845f;
    float resc[4];
#pragma unroll
    for (int j = 0; j < 4; j++) {
      s[0][j] *= sc; s[1][j] *= sc;
      float mx = fmaxf(s[0][j], s[1][j]);
      mx = fmaxf(mx, __shfl_xor(mx, 1)); mx = fmaxf(mx, __shfl_xor(mx, 2));
      mx = fmaxf(mx, __shfl_xor(mx, 4)); mx = fmaxf(mx, __shfl_xor(mx, 8));
      const float mnew = fmaxf(mrun[j], mx);
      resc[j] = __expf(mrun[j] - mnew);
      float p0 = __expf(s[0][j] - mnew), p1 = __expf(s[1][j] - mnew);
      s[0][j] = p0; s[1][j] = p1;
      float rsum = p0 + p1;
      rsum += __shfl_xor(rsum, 1); rsum += __shfl_xor(rsum, 2);
      rsum += __shfl_xor(rsum, 4); rsum += __shfl_xor(rsum, 8);
      lrun[j] = lrun[j] * resc[j] + rsum;
      mrun[j] = mnew;
    }
#pragma unroll
    for (int dt = 0; dt < 8; dt++)
#pragma unroll
      for (int j = 0; j < 4; j++) oacc[dt][j] *= resc[j];
#pragma unroll
    for (int nb = 0; nb < 2; nb++)
#pragma unroll
      for (int j = 0; j < 4; j++) pw[(lg * 4 + j) * 32 + nb * 16 + lr] = (bf16_t)s[nb][j];
    bf16x8 pa = *(const bf16x8*)&pw[lr * 32 + lg * 8];
    const bf16_t* vp = vbase + kv0 + lg * 8;
#pragma unroll
    for (int dt = 0; dt < 8; dt++) {
      bf16x8 vf = *(const bf16x8*)(vp + (size_t)dt * 16 * 2048);
      oacc[dt] = mfma16(pa, vf, oacc[dt]);
    }
  }
#pragma unroll
  for (int j = 0; j < 4; j++) {
    const float inv = 1.f / lrun[j];
    const size_t rbase = (tok0 + lg * 4 + j) * 2048 + h * 128 + lr;
#pragma unroll
    for (int dt = 0; dt < 8; dt++) out[rbase + dt * 16] = (bf16_t)(oacc[dt][j] * inv);
  }
}

// ---------------- fused residual + LayerNorm ----------------
__global__ __launch_bounds__(256) void ln_k(
    const float* __restrict__ X, const float* __restrict__ R,
    const float* __restrict__ G, const float* __restrict__ Bt,
    float* __restrict__ O32, bf16_t* __restrict__ O16) {
  const int t = blockIdx.x, tid = threadIdx.x;
  const float4* xp = (const float4*)(X + (size_t)t * 2048);
  const float4* rp = (const float4*)(R + (size_t)t * 2048);
  float4 v0 = xp[tid], w0 = rp[tid];
  float4 v1 = xp[tid + 256], w1 = rp[tid + 256];
  v0.x += w0.x; v0.y += w0.y; v0.z += w0.z; v0.w += w0.w;
  v1.x += w1.x; v1.y += w1.y; v1.z += w1.z; v1.w += w1.w;
  float sum = v0.x + v0.y + v0.z + v0.w + v1.x + v1.y + v1.z + v1.w;
  float sq = v0.x * v0.x + v0.y * v0.y + v0.z * v0.z + v0.w * v0.w +
             v1.x * v1.x + v1.y * v1.y + v1.z * v1.z + v1.w * v1.w;
  for (int d = 1; d < 64; d <<= 1) { sum += __shfl_xor(sum, d); sq += __shfl_xor(sq, d); }
  __shared__ float s1[4], s2[4];
  const int wv = tid >> 6, lane = tid & 63;
  if (lane == 0) { s1[wv] = sum; s2[wv] = sq; }
  __syncthreads();
  const float tot = s1[0] + s1[1] + s1[2] + s1[3];
  const float tsq = s2[0] + s2[1] + s2[2] + s2[3];
  const float mu = tot * (1.f / 2048.f);
  const float var = tsq * (1.f / 2048.f) - mu * mu;
  const float rs = 1.f / sqrtf(var + 1e-5f);
  const float4* gp = (const float4*)G;
  const float4* bp = (const float4*)Bt;
  float4 g0 = gp[tid], g1v = gp[tid + 256], b0 = bp[tid], b1v = bp[tid + 256];
  float4 o0, o1;
  o0.x = (v0.x - mu) * rs * g0.x + b0.x; o0.y = (v0.y - mu) * rs * g0.y + b0.y;
  o0.z = (v0.z - mu) * rs * g0.z + b0.z; o0.w = (v0.w - mu) * rs * g0.w + b0.w;
  o1.x = (v1.x - mu) * rs * g1v.x + b1v.x; o1.y = (v1.y - mu) * rs * g1v.y + b1v.y;
  o1.z = (v1.z - mu) * rs * g1v.z + b1v.z; o1.w = (v1.w - mu) * rs * g1v.w + b1v.w;
  ((float4*)(O32 + (size_t)t * 2048))[tid] = o0;
  ((float4*)(O32 + (size_t)t * 2048))[tid + 256] = o1;
  if (O16) {
    bf16x4 h0, h1;
    h0[0] = (bf16_t)o0.x; h0[1] = (bf16_t)o0.y; h0[2] = (bf16_t)o0.z; h0[3] = (bf16_t)o0.w;
    h1[0] = (bf16_t)o1.x; h1[1] = (bf16_t)o1.y; h1[2] = (bf16_t)o1.z; h1[3] = (bf16_t)o1.w;
    *(bf16x4*)&O16[(size_t)t * 2048 + tid * 4] = h0;
    *(bf16x4*)&O16[(size_t)t * 2048 + 1024 + tid * 4] = h1;
  }
}

// ---------------- launch ----------------
extern "C" void kernel_launch(void* const* d_in, const int* in_sizes, int n_in,
                              void* d_out, int out_size, void* d_ws, size_t ws_size,
                              hipStream_t stream) {
  const float* x  = (const float*)d_in[0];
  const float* Wq = (const float*)d_in[1];
  const float* Wk = (const float*)d_in[2];
  const float* Wv = (const float*)d_in[3];
  const float* Wo = (const float*)d_in[4];
  const float* W1 = (const float*)d_in[5];
  const float* W2 = (const float*)d_in[6];
  const float* g1 = (const float*)d_in[7];
  const float* b1 = (const float*)d_in[8];
  const float* g2 = (const float*)d_in[9];
  const float* b2 = (const float*)d_in[10];
  float* out = (float*)d_out;
  char* ws = (char*)d_ws;

  constexpr size_t SZB = (size_t)4096 * 2048 * 2;  // one bf16 [4096][2048] buffer
  bf16_t* xh = (bf16_t*)(ws + 0 * SZB);
  bf16_t* xl = (bf16_t*)(ws + 1 * SZB);
  bf16_t* qh = (bf16_t*)(ws + 2 * SZB);
  bf16_t* ql = (bf16_t*)(ws + 3 * SZB);
  bf16_t* kh = (bf16_t*)(ws + 4 * SZB);
  bf16_t* kl = (bf16_t*)(ws + 5 * SZB);
  bf16_t* vt = (bf16_t*)(ws + 6 * SZB);
  bf16_t* at = (bf16_t*)(ws + 7 * SZB);
  float* o32 = (float*)(ws + 8 * SZB);
  bf16_t* wt = (bf16_t*)(ws + 8 * SZB + (size_t)4096 * 2048 * 4);
  double* red = (double*)(ws + 8 * SZB + (size_t)4096 * 2048 * 4 + (size_t)8192 * 2048 * 2);
  double* sums = red + 1024;
  // aliases (phase-disjoint lifetimes)
  float* h1 = (float*)ws;       // over xh+xl
  bf16_t* h1b = qh;             // over qh
  bf16_t* f1 = kh;              // over kh,kl,vt,at (exactly 67.1 MB)
  float* g32 = o32;             // over o32
  (void)in_sizes; (void)n_in; (void)out_size; (void)ws_size;

  const float* Wm[6] = {Wq, Wk, Wv, Wo, W1, W2};
  const int nW[6] = {4194304, 4194304, 4194304, 4194304, 16777216, 16777216};
  for (int i = 0; i < 6; i++) {
    abssum_stage1<<<1024, 256, 0, stream>>>(Wm[i], nW[i] / 4, red);
    abssum_stage2<<<1, 256, 0, stream>>>(red, sums + i);
  }
  split_x_k<<<8192, 256, 0, stream>>>(x, xh, xl);

  // Q
  ternarize_k<<<4096, 256, 0, stream>>>(Wq, wt, sums + 0, 4194304.0);
  gemm_tn<0, true><<<dim3(16, 32), 256, 0, stream>>>(xh, xl, wt, qh, ql, 4096, 2048, 2048);
  // K
  ternarize_k<<<4096, 256, 0, stream>>>(Wk, wt, sums + 1, 4194304.0);
  gemm_tn<0, true><<<dim3(16, 32), 256, 0, stream>>>(xh, xl, wt, kh, kl, 4096, 2048, 2048);
  // V (plain A, transposed store)
  ternarize_k<<<4096, 256, 0, stream>>>(Wv, wt, sums + 2, 4194304.0);
  gemm_tn<1, false><<<dim3(16, 32), 256, 0, stream>>>(xh, nullptr, wt, vt, nullptr, 4096, 2048, 2048);
  // attention
  attn_k<<<dim3(32, 32), 256, 0, stream>>>(qh, ql, kh, kl, vt, at);
  // O projection -> f32
  ternarize_k<<<4096, 256, 0, stream>>>(Wo, wt, sums + 3, 4194304.0);
  gemm_tn<2, false><<<dim3(16, 32), 256, 0, stream>>>(at, nullptr, wt, o32, nullptr, 4096, 2048, 2048);
  // LN1 (residual x + o32) -> h1 (f32) + h1b (bf16)
  ln_k<<<4096, 256, 0, stream>>>(x, o32, g1, b1, h1, h1b);
  // FF1 + relu
  ternarize_k<<<16384, 256, 0, stream>>>(W1, wt, sums + 4, 16777216.0);
  gemm_tn<3, false><<<dim3(64, 32), 256, 0, stream>>>(h1b, nullptr, wt, f1, nullptr, 4096, 8192, 2048);
  // FF2 -> f32
  ternarize_k<<<16384, 256, 0, stream>>>(W2, wt, sums + 5, 16777216.0);
  gemm_tn<2, false><<<dim3(16, 32), 256, 0, stream>>>(f1, nullptr, wt, g32, nullptr, 4096, 2048, 8192);
  // LN2 -> out
  ln_k<<<4096, 256, 0, stream>>>(h1, g32, g2, b2, out, nullptr);
}

// Round 2
// 1110.099 us; speedup vs baseline: 1.4012x; 1.4012x over previous
//
#include <hip/hip_runtime.h>
#include <hip/hip_bf16.h>

typedef __bf16 bf16_t;
typedef __bf16 bf16x8 __attribute__((ext_vector_type(8)));
typedef __bf16 bf16x4 __attribute__((ext_vector_type(4)));
typedef float f32x4 __attribute__((ext_vector_type(4)));
typedef int i32x4 __attribute__((ext_vector_type(4)));

__device__ __forceinline__ f32x4 mfma16(bf16x8 a, bf16x8 b, f32x4 c) {
  return __builtin_amdgcn_mfma_f32_16x16x32_bf16(a, b, c, 0, 0, 0);
}

__device__ __forceinline__ void gload16(const void* g, void* l) {
  __builtin_amdgcn_global_load_lds(
      (const __attribute__((address_space(1))) void*)g,
      (__attribute__((address_space(3))) void*)l, 16, 0, 0);
}

// ---------------- ternary threshold: deterministic fp64 two-stage reduction ----------------
__global__ void abssum_stage1(const float* __restrict__ W, int n4, double* __restrict__ partial) {
  __shared__ double sd[256];
  const int tid = threadIdx.x;
  double s = 0.0;
  for (int i = blockIdx.x * 256 + tid; i < n4; i += gridDim.x * 256) {
    float4 v = ((const float4*)W)[i];
    s += (double)fabsf(v.x); s += (double)fabsf(v.y);
    s += (double)fabsf(v.z); s += (double)fabsf(v.w);
  }
  sd[tid] = s; __syncthreads();
  for (int st = 128; st > 0; st >>= 1) { if (tid < st) sd[tid] += sd[tid + st]; __syncthreads(); }
  if (tid == 0) partial[blockIdx.x] = sd[0];
}

__global__ void abssum_stage2(const double* __restrict__ partial, double* __restrict__ out) {
  __shared__ double sd[256];
  const int tid = threadIdx.x;
  double s = partial[tid] + partial[tid + 256] + partial[tid + 512] + partial[tid + 768];
  sd[tid] = s; __syncthreads();
  for (int st = 128; st > 0; st >>= 1) { if (tid < st) sd[tid] += sd[tid + st]; __syncthreads(); }
  if (tid == 0) out[0] = sd[0];
}

__global__ void ternarize_k(const float* __restrict__ W, bf16_t* __restrict__ out,
                            const double* __restrict__ sum, double n) {
  const double thr = sum[0] / n;
  const int i = blockIdx.x * 256 + threadIdx.x;  // float4 index; grid sized exactly
  float4 v = ((const float4*)W)[i];
  bf16x4 o;
  float t;
  t = ((double)fabsf(v.x) > thr) ? (v.x > 0.f ? 1.f : -1.f) : 0.f; o[0] = (bf16_t)t;
  t = ((double)fabsf(v.y) > thr) ? (v.y > 0.f ? 1.f : -1.f) : 0.f; o[1] = (bf16_t)t;
  t = ((double)fabsf(v.z) > thr) ? (v.z > 0.f ? 1.f : -1.f) : 0.f; o[2] = (bf16_t)t;
  t = ((double)fabsf(v.w) > thr) ? (v.w > 0.f ? 1.f : -1.f) : 0.f; o[3] = (bf16_t)t;
  *(bf16x4*)&out[(size_t)i * 4] = o;
}

// ---------------- x -> hi/lo bf16 split ----------------
__global__ void split_x_k(const float* __restrict__ X, bf16_t* __restrict__ xh, bf16_t* __restrict__ xl) {
  const int i = blockIdx.x * 256 + threadIdx.x;  // float4 index; total 2,097,152
  float4 v = ((const float4*)X)[i];
  bf16x4 h, l;
  h[0] = (bf16_t)v.x; l[0] = (bf16_t)(v.x - (float)h[0]);
  h[1] = (bf16_t)v.y; l[1] = (bf16_t)(v.y - (float)h[1]);
  h[2] = (bf16_t)v.z; l[2] = (bf16_t)(v.z - (float)h[2]);
  h[3] = (bf16_t)v.w; l[3] = (bf16_t)(v.w - (float)h[3]);
  *(bf16x4*)&xh[(size_t)i * 4] = h;
  *(bf16x4*)&xl[(size_t)i * 4] = l;
}

// ---------------- GEMM: C[t][o] = sum_k A[t][k] * W[o][k]  (W ternary bf16, [N][K] row-major) ----
// EPI: 0 = split-store (C0=hi bf16, C1=lo bf16), 1 = vT transposed bf16 store,
//      2 = f32 store, 3 = relu bf16 store
template <int EPI, bool SPLITA>
__global__ __launch_bounds__(256, 2) void gemm_tn(
    const bf16_t* __restrict__ Ah, const bf16_t* __restrict__ Al,
    const bf16_t* __restrict__ Bw,
    void* __restrict__ C0, void* __restrict__ C1,
    int M, int N, int K) {
  constexpr int BK = 32;
  __shared__ __align__(16) bf16_t sA[128 * BK];
  __shared__ __align__(16) bf16_t sA2[SPLITA ? 128 * BK : 8];
  __shared__ __align__(16) bf16_t sB[128 * BK];

  const int tid = threadIdx.x;
  const size_t Ks = (size_t)K;
  const size_t m0 = (size_t)blockIdx.y * 128, n0 = (size_t)blockIdx.x * 128;
  const int lane = tid & 63, wv = tid >> 6, lr = lane & 15, lg = lane >> 4;
  const int wr = wv >> 1, wc = wv & 1;
  const int f0 = tid, f1 = tid + 256;
  const int r0 = f0 >> 2, c0 = (f0 & 3) * 8, r1 = f1 >> 2, c1 = (f1 & 3) * 8;

  f32x4 acc[4][4] = {};
  i32x4 a0, a1, a2, a3, b0, b1;
  const int nt = K / BK;

  auto LOADT = [&](int kt) {
    size_t ko = (size_t)kt * BK;
    a0 = *(const i32x4*)(Ah + (m0 + r0) * Ks + ko + c0);
    a1 = *(const i32x4*)(Ah + (m0 + r1) * Ks + ko + c1);
    if constexpr (SPLITA) {
      a2 = *(const i32x4*)(Al + (m0 + r0) * Ks + ko + c0);
      a3 = *(const i32x4*)(Al + (m0 + r1) * Ks + ko + c1);
    }
    b0 = *(const i32x4*)(Bw + (n0 + r0) * Ks + ko + c0);
    b1 = *(const i32x4*)(Bw + (n0 + r1) * Ks + ko + c1);
  };
  auto WRT = [&]() {
    *(i32x4*)&sA[f0 * 8] = a0; *(i32x4*)&sA[f1 * 8] = a1;
    if constexpr (SPLITA) { *(i32x4*)&sA2[f0 * 8] = a2; *(i32x4*)&sA2[f1 * 8] = a3; }
    *(i32x4*)&sB[f0 * 8] = b0; *(i32x4*)&sB[f1 * 8] = b1;
  };

  LOADT(0); WRT(); __syncthreads();
  for (int kt = 0; kt < nt; kt++) {
    if (kt + 1 < nt) LOADT(kt + 1);
    bf16x8 afh[4], bfr[4];
#pragma unroll
    for (int n = 0; n < 4; n++) bfr[n] = *(const bf16x8*)&sB[(wc * 64 + n * 16 + lr) * BK + lg * 8];
#pragma unroll
    for (int m = 0; m < 4; m++) afh[m] = *(const bf16x8*)&sA[(wr * 64 + m * 16 + lr) * BK + lg * 8];
#pragma unroll
    for (int m = 0; m < 4; m++)
#pragma unroll
      for (int n = 0; n < 4; n++) acc[m][n] = mfma16(afh[m], bfr[n], acc[m][n]);
    if constexpr (SPLITA) {
#pragma unroll
      for (int m = 0; m < 4; m++) afh[m] = *(const bf16x8*)&sA2[(wr * 64 + m * 16 + lr) * BK + lg * 8];
#pragma unroll
      for (int m = 0; m < 4; m++)
#pragma unroll
        for (int n = 0; n < 4; n++) acc[m][n] = mfma16(afh[m], bfr[n], acc[m][n]);
    }
    if (kt + 1 < nt) { __syncthreads(); WRT(); __syncthreads(); }
  }

  const int row0 = (int)m0 + wr * 64, colb = (int)n0 + wc * 64;
#pragma unroll
  for (int m = 0; m < 4; m++)
#pragma unroll
    for (int n = 0; n < 4; n++)
#pragma unroll
      for (int j = 0; j < 4; j++) {
        const int r = row0 + m * 16 + lg * 4 + j;
        const int c = colb + n * 16 + lr;
        const float v = acc[m][n][j];
        if constexpr (EPI == 0) {
          bf16_t hi = (bf16_t)v;
          ((bf16_t*)C0)[(size_t)r * N + c] = hi;
          ((bf16_t*)C1)[(size_t)r * N + c] = (bf16_t)(v - (float)hi);
        } else if constexpr (EPI == 1) {
          const int bb = r >> 11, ss = r & 2047;
          ((bf16_t*)C0)[((size_t)bb * 2048 + c) * 2048 + ss] = (bf16_t)v;
        } else if constexpr (EPI == 2) {
          ((float*)C0)[(size_t)r * N + c] = v;
        } else {
          ((bf16_t*)C0)[(size_t)r * N + c] = (bf16_t)fmaxf(v, 0.f);
        }
      }
}

// ---------------- flash attention, v2 ----------------
// 4 waves, q-tile 64 (16 rows/wave), KVBLK=64.
// K hi+lo staged in LDS (double-buffered, global_load_lds, XOR-swizzled via
// pre-swizzled global source), counted-vmcnt prefetch across raw barriers.
// LDS[r][u] (u = 16B unit 0..15) holds global unit u ^ (r&7) of K-row r.
// P-transpose buffer per wave, XOR-swizzled the same way (8 units/row).
__global__ __launch_bounds__(256) void attn_k(
    const bf16_t* __restrict__ qh, const bf16_t* __restrict__ ql,
    const bf16_t* __restrict__ kh, const bf16_t* __restrict__ kl,
    const bf16_t* __restrict__ vT, bf16_t* __restrict__ out) {
  __shared__ __align__(16) bf16_t sKh[2 * 8192];   // 2 x [64][128]
  __shared__ __align__(16) bf16_t sKl[2 * 8192];
  __shared__ __align__(16) bf16_t plds[4][1024];   // per-wave [16 rows][64 kv]

  const int qt = blockIdx.x, bh = blockIdx.y;
  const int b = bh >> 4, h = bh & 15;
  const int wv = threadIdx.x >> 6, lane = threadIdx.x & 63, lr = lane & 15, lg = lane >> 4;
  const size_t tok0 = (size_t)b * 2048 + qt * 64 + wv * 16;
  bf16_t* pw = &plds[wv][0];

  // stage K chunk (64 rows x 128 d, hi+lo) into LDS buffer bufi; 8 loads/wave
  auto STAGE = [&](int bufi, int kv0n) {
#pragma unroll
    for (int i = 0; i < 4; i++) {
      const int tt = wv * 4 + i;                    // instr idx 0..15, 4 rows each
      const int r = tt * 4 + (lane >> 4);           // K-row 0..63
      const int ce = ((lane & 15) ^ (r & 7)) * 8;   // pre-swizzled source column
      const size_t gofs = ((size_t)b * 2048 + kv0n + r) * 2048 + h * 128 + ce;
      gload16(kh + gofs, (void*)&sKh[bufi * 8192 + tt * 512]);
      gload16(kl + gofs, (void*)&sKl[bufi * 8192 + tt * 512]);
    }
  };

  bf16x8 qhf[4], qlf[4];
  {
    const bf16_t* qp = qh + (tok0 + lr) * 2048 + h * 128 + lg * 8;
    const bf16_t* qp2 = ql + (tok0 + lr) * 2048 + h * 128 + lg * 8;
#pragma unroll
    for (int ks = 0; ks < 4; ks++) {
      qhf[ks] = *(const bf16x8*)(qp + ks * 32);
      qlf[ks] = *(const bf16x8*)(qp2 + ks * 32);
    }
  }
  f32x4 oacc[8] = {};
  float mrun[4] = {-1e30f, -1e30f, -1e30f, -1e30f};
  float lrun[4] = {0.f, 0.f, 0.f, 0.f};
  const bf16_t* vbase = vT + ((size_t)b * 2048 + h * 128 + lr) * 2048;
  const float sc = 0.08838834764831845f;

  STAGE(0, 0);
  for (int c = 0; c < 32; c++) {
    const int kv0 = c * 64;
    if (c + 1 < 32) {
      STAGE((c + 1) & 1, kv0 + 64);
      asm volatile("s_waitcnt vmcnt(8)" ::: "memory");  // own prev-chunk stage done
    } else {
      asm volatile("s_waitcnt vmcnt(0)" ::: "memory");
    }
    __builtin_amdgcn_s_barrier();                       // all waves' stage(c) done

    const int bufo = (c & 1) * 8192;
    // ---- QK^T: 3-term split precision, 4 independent 12-MFMA chains ----
    f32x4 s[4] = {};
#pragma unroll
    for (int nb = 0; nb < 4; nb++) {
      const int rbase = bufo + (nb * 16 + lr) * 128;
#pragma unroll
      for (int ks = 0; ks < 4; ks++) {
        const int u = (((ks * 4 + lg) ^ (lr & 7)) * 8);
        bf16x8 kf = *(const bf16x8*)&sKh[rbase + u];
        bf16x8 kg = *(const bf16x8*)&sKl[rbase + u];
        s[nb] = mfma16(qhf[ks], kf, s[nb]);
        s[nb] = mfma16(qlf[ks], kf, s[nb]);
        s[nb] = mfma16(qhf[ks], kg, s[nb]);
      }
    }
#pragma unroll
    for (int nb = 0; nb < 4; nb++) s[nb] *= sc;

    // ---- online softmax (reduce over 16 lr lanes) ----
    float resc[4];
#pragma unroll
    for (int j = 0; j < 4; j++) {
      float mx = fmaxf(fmaxf(s[0][j], s[1][j]), fmaxf(s[2][j], s[3][j]));
      mx = fmaxf(mx, __shfl_xor(mx, 1)); mx = fmaxf(mx, __shfl_xor(mx, 2));
      mx = fmaxf(mx, __shfl_xor(mx, 4)); mx = fmaxf(mx, __shfl_xor(mx, 8));
      const float mnew = fmaxf(mrun[j], mx);
      resc[j] = __expf(mrun[j] - mnew);
      float rsum = 0.f;
#pragma unroll
      for (int nb = 0; nb < 4; nb++) {
        const float p = __expf(s[nb][j] - mnew);
        s[nb][j] = p;
        rsum += p;
      }
      rsum += __shfl_xor(rsum, 1); rsum += __shfl_xor(rsum, 2);
      rsum += __shfl_xor(rsum, 4); rsum += __shfl_xor(rsum, 8);
      lrun[j] = lrun[j] * resc[j] + rsum;
      mrun[j] = mnew;
    }
#pragma unroll
    for (int dt = 0; dt < 8; dt++)
#pragma unroll
      for (int j = 0; j < 4; j++) oacc[dt][j] *= resc[j];

    // ---- P transpose through swizzled per-wave LDS ----
#pragma unroll
    for (int nb = 0; nb < 4; nb++) {
      const int unit = nb * 2 + (lr >> 3);
#pragma unroll
      for (int j = 0; j < 4; j++) {
        const int row = lg * 4 + j;
        pw[row * 64 + ((unit ^ (row & 7)) * 8) + (lr & 7)] = (bf16_t)s[nb][j];
      }
    }
    bf16x8 pa0 = *(const bf16x8*)&pw[lr * 64 + ((lg ^ (lr & 7)) * 8)];
    bf16x8 pa1 = *(const bf16x8*)&pw[lr * 64 + (((4 + lg) ^ (lr & 7)) * 8)];

    // ---- PV (V direct from global vT, L2-resident) ----
    const bf16_t* vp = vbase + kv0 + lg * 8;
#pragma unroll
    for (int dt = 0; dt < 8; dt++) {
      bf16x8 v0 = *(const bf16x8*)(vp + (size_t)dt * 16 * 2048);
      bf16x8 v1 = *(const bf16x8*)(vp + (size_t)dt * 16 * 2048 + 32);
      oacc[dt] = mfma16(pa0, v0, oacc[dt]);
      oacc[dt] = mfma16(pa1, v1, oacc[dt]);
    }
    asm volatile("" ::: "memory");
    __builtin_amdgcn_s_barrier();                       // buf c&1 free for restage
  }

#pragma unroll
  for (int j = 0; j < 4; j++) {
    const float inv = 1.f / lrun[j];
    const size_t rbase = (tok0 + lg * 4 + j) * 2048 + h * 128 + lr;
#pragma unroll
    for (int dt = 0; dt < 8; dt++) out[rbase + dt * 16] = (bf16_t)(oacc[dt][j] * inv);
  }
}

// ---------------- fused residual + LayerNorm ----------------
__global__ __launch_bounds__(256) void ln_k(
    const float* __restrict__ X, const float* __restrict__ R,
    const float* __restrict__ G, const float* __restrict__ Bt,
    float* __restrict__ O32, bf16_t* __restrict__ O16) {
  const int t = blockIdx.x, tid = threadIdx.x;
  const float4* xp = (const float4*)(X + (size_t)t * 2048);
  const float4* rp = (const float4*)(R + (size_t)t * 2048);
  float4 v0 = xp[tid], w0 = rp[tid];
  float4 v1 = xp[tid + 256], w1 = rp[tid + 256];
  v0.x += w0.x; v0.y += w0.y; v0.z += w0.z; v0.w += w0.w;
  v1.x += w1.x; v1.y += w1.y; v1.z += w1.z; v1.w += w1.w;
  float sum = v0.x + v0.y + v0.z + v0.w + v1.x + v1.y + v1.z + v1.w;
  float sq = v0.x * v0.x + v0.y * v0.y + v0.z * v0.z + v0.w * v0.w +
             v1.x * v1.x + v1.y * v1.y + v1.z * v1.z + v1.w * v1.w;
  for (int d = 1; d < 64; d <<= 1) { sum += __shfl_xor(sum, d); sq += __shfl_xor(sq, d); }
  __shared__ float s1[4], s2[4];
  const int wv = tid >> 6, lane = tid & 63;
  if (lane == 0) { s1[wv] = sum; s2[wv] = sq; }
  __syncthreads();
  const float tot = s1[0] + s1[1] + s1[2] + s1[3];
  const float tsq = s2[0] + s2[1] + s2[2] + s2[3];
  const float mu = tot * (1.f / 2048.f);
  const float var = tsq * (1.f / 2048.f) - mu * mu;
  const float rs = 1.f / sqrtf(var + 1e-5f);
  const float4* gp = (const float4*)G;
  const float4* bp = (const float4*)Bt;
  float4 g0 = gp[tid], g1v = gp[tid + 256], b0 = bp[tid], b1v = bp[tid + 256];
  float4 o0, o1;
  o0.x = (v0.x - mu) * rs * g0.x + b0.x; o0.y = (v0.y - mu) * rs * g0.y + b0.y;
  o0.z = (v0.z - mu) * rs * g0.z + b0.z; o0.w = (v0.w - mu) * rs * g0.w + b0.w;
  o1.x = (v1.x - mu) * rs * g1v.x + b1v.x; o1.y = (v1.y - mu) * rs * g1v.y + b1v.y;
  o1.z = (v1.z - mu) * rs * g1v.z + b1v.z; o1.w = (v1.w - mu) * rs * g1v.w + b1v.w;
  ((float4*)(O32 + (size_t)t * 2048))[tid] = o0;
  ((float4*)(O32 + (size_t)t * 2048))[tid + 256] = o1;
  if (O16) {
    bf16x4 h0, h1;
    h0[0] = (bf16_t)o0.x; h0[1] = (bf16_t)o0.y; h0[2] = (bf16_t)o0.z; h0[3] = (bf16_t)o0.w;
    h1[0] = (bf16_t)o1.x; h1[1] = (bf16_t)o1.y; h1[2] = (bf16_t)o1.z; h1[3] = (bf16_t)o1.w;
    *(bf16x4*)&O16[(size_t)t * 2048 + tid * 4] = h0;
    *(bf16x4*)&O16[(size_t)t * 2048 + 1024 + tid * 4] = h1;
  }
}

// ---------------- launch ----------------
extern "C" void kernel_launch(void* const* d_in, const int* in_sizes, int n_in,
                              void* d_out, int out_size, void* d_ws, size_t ws_size,
                              hipStream_t stream) {
  const float* x  = (const float*)d_in[0];
  const float* Wq = (const float*)d_in[1];
  const float* Wk = (const float*)d_in[2];
  const float* Wv = (const float*)d_in[3];
  const float* Wo = (const float*)d_in[4];
  const float* W1 = (const float*)d_in[5];
  const float* W2 = (const float*)d_in[6];
  const float* g1 = (const float*)d_in[7];
  const float* b1 = (const float*)d_in[8];
  const float* g2 = (const float*)d_in[9];
  const float* b2 = (const float*)d_in[10];
  float* out = (float*)d_out;
  char* ws = (char*)d_ws;

  constexpr size_t SZB = (size_t)4096 * 2048 * 2;  // one bf16 [4096][2048] buffer
  bf16_t* xh = (bf16_t*)(ws + 0 * SZB);
  bf16_t* xl = (bf16_t*)(ws + 1 * SZB);
  bf16_t* qh = (bf16_t*)(ws + 2 * SZB);
  bf16_t* ql = (bf16_t*)(ws + 3 * SZB);
  bf16_t* kh = (bf16_t*)(ws + 4 * SZB);
  bf16_t* kl = (bf16_t*)(ws + 5 * SZB);
  bf16_t* vt = (bf16_t*)(ws + 6 * SZB);
  bf16_t* at = (bf16_t*)(ws + 7 * SZB);
  float* o32 = (float*)(ws + 8 * SZB);
  bf16_t* wt = (bf16_t*)(ws + 8 * SZB + (size_t)4096 * 2048 * 4);
  double* red = (double*)(ws + 8 * SZB + (size_t)4096 * 2048 * 4 + (size_t)8192 * 2048 * 2);
  double* sums = red + 1024;
  // aliases (phase-disjoint lifetimes)
  float* h1 = (float*)ws;       // over xh+xl
  bf16_t* h1b = qh;             // over qh
  bf16_t* f1 = kh;              // over kh,kl,vt,at (exactly 67.1 MB)
  float* g32 = o32;             // over o32
  (void)in_sizes; (void)n_in; (void)out_size; (void)ws_size;

  const float* Wm[6] = {Wq, Wk, Wv, Wo, W1, W2};
  const int nW[6] = {4194304, 4194304, 4194304, 4194304, 16777216, 16777216};
  for (int i = 0; i < 6; i++) {
    abssum_stage1<<<1024, 256, 0, stream>>>(Wm[i], nW[i] / 4, red);
    abssum_stage2<<<1, 256, 0, stream>>>(red, sums + i);
  }
  split_x_k<<<8192, 256, 0, stream>>>(x, xh, xl);

  // Q
  ternarize_k<<<4096, 256, 0, stream>>>(Wq, wt, sums + 0, 4194304.0);
  gemm_tn<0, true><<<dim3(16, 32), 256, 0, stream>>>(xh, xl, wt, qh, ql, 4096, 2048, 2048);
  // K
  ternarize_k<<<4096, 256, 0, stream>>>(Wk, wt, sums + 1, 4194304.0);
  gemm_tn<0, true><<<dim3(16, 32), 256, 0, stream>>>(xh, xl, wt, kh, kl, 4096, 2048, 2048);
  // V (plain A, transposed store)
  ternarize_k<<<4096, 256, 0, stream>>>(Wv, wt, sums + 2, 4194304.0);
  gemm_tn<1, false><<<dim3(16, 32), 256, 0, stream>>>(xh, nullptr, wt, vt, nullptr, 4096, 2048, 2048);
  // attention
  attn_k<<<dim3(32, 32), 256, 0, stream>>>(qh, ql, kh, kl, vt, at);
  // O projection -> f32
  ternarize_k<<<4096, 256, 0, stream>>>(Wo, wt, sums + 3, 4194304.0);
  gemm_tn<2, false><<<dim3(16, 32), 256, 0, stream>>>(at, nullptr, wt, o32, nullptr, 4096, 2048, 2048);
  // LN1 (residual x + o32) -> h1 (f32) + h1b (bf16)
  ln_k<<<4096, 256, 0, stream>>>(x, o32, g1, b1, h1, h1b);
  // FF1 + relu
  ternarize_k<<<16384, 256, 0, stream>>>(W1, wt, sums + 4, 16777216.0);
  gemm_tn<3, false><<<dim3(64, 32), 256, 0, stream>>>(h1b, nullptr, wt, f1, nullptr, 4096, 8192, 2048);
  // FF2 -> f32
  ternarize_k<<<16384, 256, 0, stream>>>(W2, wt, sums + 5, 16777216.0);
  gemm_tn<2, false><<<dim3(16, 32), 256, 0, stream>>>(f1, nullptr, wt, g32, nullptr, 4096, 2048, 8192);
  // LN2 -> out
  ln_k<<<4096, 256, 0, stream>>>(h1, g32, g2, b2, out, nullptr);
}